// Round 2
// baseline (3443.702 us; speedup 1.0000x reference)
//
#include <hip/hip_runtime.h>

#define EPSV 1e-5f

__device__ __forceinline__ float fast_rcp(float x) { return __builtin_amdgcn_rcpf(x); }
__device__ __forceinline__ float sigm(float x) { return fast_rcp(1.0f + __expf(-x)); }
__device__ __forceinline__ float tanhfast(float x) {
    float e = __expf(2.0f * x);
    return 1.0f - 2.0f * fast_rcp(e + 1.0f);
}

// ---------------- pack w2 (32,64,7) -> w2t2[(i*32+o)*8 + k] (k<7, pad 0) ----------------
__global__ void pack_w2_kernel(const float* __restrict__ w2, float* __restrict__ w2t2) {
    int j = blockIdx.x * 256 + threadIdx.x;
    if (j < 16384) {
        int i = j >> 8;
        int o = (j >> 3) & 31;
        int k = j & 7;
        w2t2[j] = (k < 7) ? w2[o * 448 + i * 7 + k] : 0.0f;
    }
}

// ---------------- CNN: one block per window (b,t) ----------------
// a1: stride 60, halo 3 (slot = i*60 + 3 + p, zeros at [0..2] & [53..59]) -> conv2 reads
//     float4-aligned at base i*60 + 8*pg.
// a2: stride 56, halo 2 (slot = i*56 + 2 + p, zeros at [0..1] & [52..55]) -> conv3 reads
//     float4-aligned at base i*56 + 4*pg.
__global__ __launch_bounds__(256) void cnn_kernel(
    const float* __restrict__ x,
    const float* __restrict__ w1, const float* __restrict__ b1,
    const float* __restrict__ g1, const float* __restrict__ be1,
    const float* __restrict__ m1, const float* __restrict__ v1,
    const float* __restrict__ b2,
    const float* __restrict__ g2, const float* __restrict__ be2,
    const float* __restrict__ m2, const float* __restrict__ v2,
    const float* __restrict__ w3, const float* __restrict__ b3,
    const float* __restrict__ g3, const float* __restrict__ be3,
    const float* __restrict__ m3, const float* __restrict__ v3,
    const float* __restrict__ w2t2,
    float* __restrict__ feats)
{
    __shared__ float winh[64];               // window + conv1 halo (4 each side)
    __shared__ float w1t[9 * 64];            // [k][o]
    __shared__ float4 w3s4[512];             // [(i*16+o)] k=0..3
    __shared__ float  w3s1[512];             // [(i*16+o)] k=4
    __shared__ __align__(16) float a1[64 * 60 + 16];
    __shared__ __align__(16) float a2[32 * 56 + 16];
    __shared__ float s1[64], t1[64], s2[32], t2[32], s3[16], t3[16];
    __shared__ float psum[16 * 16];

    const int tid = threadIdx.x;
    const int w = blockIdx.x;
    const int b = w >> 11;
    const int t = w & 2047;

    // ---- staging ----
    for (int idx = tid; idx < 576; idx += 256) {
        int o = idx / 9, k = idx % 9;
        w1t[k * 64 + o] = w1[idx];
    }
    for (int idx = tid; idx < 512; idx += 256) {
        int i = idx >> 4, o = idx & 15;
        int base = o * 160 + i * 5;
        w3s4[idx] = make_float4(w3[base], w3[base + 1], w3[base + 2], w3[base + 3]);
        w3s1[idx] = w3[base + 4];
    }
    if (tid < 64) {
        float s = g1[tid] * rsqrtf(v1[tid] + EPSV);
        s1[tid] = s;
        t1[tid] = (b1[tid] - m1[tid]) * s + be1[tid];
    } else if (tid < 96) {
        int o = tid - 64;
        float s = g2[o] * rsqrtf(v2[o] + EPSV);
        s2[o] = s;
        t2[o] = (b2[o] - m2[o]) * s + be2[o];
    } else if (tid < 112) {
        int o = tid - 96;
        float s = g3[o] * rsqrtf(v3[o] + EPSV);
        s3[o] = s;
        t3[o] = (b3[o] - m3[o]) * s + be3[o];
    }
    if (tid < 64) {
        winh[tid] = 0.0f;
        float* r = &a1[tid * 60];
        r[0] = 0.f; r[1] = 0.f; r[2] = 0.f;
        r[53] = 0.f; r[54] = 0.f; r[55] = 0.f; r[56] = 0.f; r[57] = 0.f; r[58] = 0.f; r[59] = 0.f;
    }
    if (tid < 32) {
        float* r = &a2[tid * 56];
        r[0] = 0.f; r[1] = 0.f;
        r[52] = 0.f; r[53] = 0.f; r[54] = 0.f; r[55] = 0.f;
    }
    __syncthreads();   // winh zeros before window overwrite
    if (tid < 50) {
        int gi = t + tid - 49;
        winh[4 + tid] = (gi >= 0) ? x[b * 2048 + gi] : 0.0f;
    }
    __syncthreads();

    // ---- conv1: 64 o x 4 pgroups of 13 ----
    {
        int o = tid >> 2, pg = tid & 3;
        int p0 = pg * 13;
        float wv[9];
        #pragma unroll
        for (int k = 0; k < 9; ++k) wv[k] = w1t[k * 64 + o];
        float sc = s1[o], tc = t1[o];
        #pragma unroll
        for (int q = 0; q < 13; ++q) {
            int p = p0 + q;
            if (p < 50) {
                float acc = 0.0f;
                #pragma unroll
                for (int k = 0; k < 9; ++k) acc = fmaf(wv[k], winh[p + k], acc);
                a1[o * 60 + 3 + p] = fmaxf(acc * sc + tc, 0.0f);
            }
        }
    }
    __syncthreads();

    // ---- conv2: 32 o x 8 pgroups of 8 positions, K = 64*7 ----
    {
        int o = tid >> 3, pg = tid & 7;
        float acc[8];
        #pragma unroll
        for (int q = 0; q < 8; ++q) acc[q] = 0.0f;
        for (int i = 0; i < 64; ++i) {
            const float4* ap = (const float4*)&a1[i * 60 + 8 * pg];
            float4 A0 = ap[0], A1 = ap[1], A2 = ap[2];
            float2 A3 = *(const float2*)&a1[i * 60 + 8 * pg + 12];
            const float4* wp = (const float4*)&w2t2[(i * 32 + o) * 8];
            float4 Wa = wp[0], Wb = wp[1];
            float av[14] = {A0.x, A0.y, A0.z, A0.w, A1.x, A1.y, A1.z, A1.w,
                            A2.x, A2.y, A2.z, A2.w, A3.x, A3.y};
            float wk[7] = {Wa.x, Wa.y, Wa.z, Wa.w, Wb.x, Wb.y, Wb.z};
            #pragma unroll
            for (int k = 0; k < 7; ++k) {
                #pragma unroll
                for (int q = 0; q < 8; ++q) acc[q] = fmaf(wk[k], av[q + k], acc[q]);
            }
        }
        float sc = s2[o], tc = t2[o];
        #pragma unroll
        for (int q = 0; q < 8; ++q) {
            int p = 8 * pg + q;
            if (p < 50) a2[o * 56 + 2 + p] = fmaxf(acc[q] * sc + tc, 0.0f);
        }
    }
    __syncthreads();

    // ---- conv3 + bn3 + relu + partial mean: 16 o x 16 pgroups of 4 ----
    {
        int o = tid & 15, pg = tid >> 4;
        float acc[4];
        #pragma unroll
        for (int q = 0; q < 4; ++q) acc[q] = 0.0f;
        for (int i = 0; i < 32; ++i) {
            float4 wa = w3s4[i * 16 + o];
            float w4 = w3s1[i * 16 + o];
            const float4* ap = (const float4*)&a2[i * 56 + 4 * pg];
            float4 Aa = ap[0], Ab = ap[1];
            float av[8] = {Aa.x, Aa.y, Aa.z, Aa.w, Ab.x, Ab.y, Ab.z, Ab.w};
            #pragma unroll
            for (int q = 0; q < 4; ++q) {
                acc[q] = fmaf(wa.x, av[q], acc[q]);
                acc[q] = fmaf(wa.y, av[q + 1], acc[q]);
                acc[q] = fmaf(wa.z, av[q + 2], acc[q]);
                acc[q] = fmaf(wa.w, av[q + 3], acc[q]);
                acc[q] = fmaf(w4,   av[q + 4], acc[q]);
            }
        }
        float sc = s3[o], tc = t3[o];
        float ps = 0.0f;
        #pragma unroll
        for (int q = 0; q < 4; ++q) {
            int p = 4 * pg + q;
            if (p < 50) ps += fmaxf(acc[q] * sc + tc, 0.0f);
        }
        psum[pg * 16 + o] = ps;
    }
    __syncthreads();

    if (tid < 16) {
        float s = 0.0f;
        #pragma unroll
        for (int pg = 0; pg < 16; ++pg) s += psum[pg * 16 + tid];
        feats[w * 16 + tid] = s * (1.0f / 50.0f);
    }
}

// ---------------- LSTM: 16 persistent blocks (one per batch), both layers pipelined ----------------
// Weights live in float4 register arrays (constant-index, fully unrolled) -> must be VGPR-resident.
// h0/h2 read via ds_read_b128 broadcast.
__global__ __launch_bounds__(512, 2) void lstm_kernel(
    const float* __restrict__ feats,
    const float* __restrict__ wih0, const float* __restrict__ whh0,
    const float* __restrict__ bih0, const float* __restrict__ bhh0,
    const float* __restrict__ wih1, const float* __restrict__ whh1,
    const float* __restrict__ bih1, const float* __restrict__ bhh1,
    float* __restrict__ h2out)
{
    __shared__ __align__(16) float h0[64];   // layer0 hidden (= layer1 input)
    __shared__ __align__(16) float h2[64];   // layer1 hidden
    __shared__ float act0[256];
    __shared__ float act1[256];

    const int tid = threadIdx.x;
    const int b = blockIdx.x;
    const int layer = tid >> 8;
    const int g = tid & 255;
    const bool is_tanh = ((g & 192) == 128);

    float4 WX[16], WH[16];
    float bb;
    if (layer == 0) {
        const float4* wh = (const float4*)(whh0 + g * 64);
        #pragma unroll
        for (int q = 0; q < 16; ++q) WH[q] = wh[q];
        const float4* wx = (const float4*)(wih0 + g * 16);
        #pragma unroll
        for (int q = 0; q < 4; ++q) WX[q] = wx[q];
        bb = bih0[g] + bhh0[g];
    } else {
        const float4* wh = (const float4*)(whh1 + g * 64);
        #pragma unroll
        for (int q = 0; q < 16; ++q) WH[q] = wh[q];
        const float4* wx = (const float4*)(wih1 + g * 64);
        #pragma unroll
        for (int q = 0; q < 16; ++q) WX[q] = wx[q];
        bb = bih1[g] + bhh1[g];
    }

    if (tid < 64) { h0[tid] = 0.0f; h2[tid] = 0.0f; }

    const float* fbase = feats + (long)b * 2048 * 16;
    float4 F[4];
    if (layer == 0) {
        const float4* fp = (const float4*)fbase;
        #pragma unroll
        for (int q = 0; q < 4; ++q) F[q] = fp[q];
    }
    float cst = 0.0f;
    const float4* h04 = (const float4*)h0;
    const float4* h24 = (const float4*)h2;
    __syncthreads();

    for (int s = 0; s <= 2048; ++s) {
        if (layer == 0) {
            if (s < 2048) {
                float a0 = bb, a1v = 0.f, a2v = 0.f, a3v = 0.f;
                #pragma unroll
                for (int q = 0; q < 4; ++q) {
                    float4 fv = F[q], wv = WX[q];
                    a0  = fmaf(fv.x, wv.x, a0);
                    a1v = fmaf(fv.y, wv.y, a1v);
                    a2v = fmaf(fv.z, wv.z, a2v);
                    a3v = fmaf(fv.w, wv.w, a3v);
                }
                #pragma unroll
                for (int q = 0; q < 16; ++q) {
                    float4 hv = h04[q], wv = WH[q];
                    a0  = fmaf(hv.x, wv.x, a0);
                    a1v = fmaf(hv.y, wv.y, a1v);
                    a2v = fmaf(hv.z, wv.z, a2v);
                    a3v = fmaf(hv.w, wv.w, a3v);
                }
                float pre = (a0 + a1v) + (a2v + a3v);
                act0[g] = is_tanh ? tanhfast(pre) : sigm(pre);
                if (s + 1 < 2048) {
                    const float4* fp = (const float4*)(fbase + (s + 1) * 16);
                    #pragma unroll
                    for (int q = 0; q < 4; ++q) F[q] = fp[q];
                }
            }
        } else {
            if (s >= 1) {
                float a0 = bb, a1v = 0.f, a2v = 0.f, a3v = 0.f;
                #pragma unroll
                for (int q = 0; q < 16; ++q) {
                    float4 hv = h04[q], wv = WX[q];
                    a0  = fmaf(hv.x, wv.x, a0);
                    a1v = fmaf(hv.y, wv.y, a1v);
                    a2v = fmaf(hv.z, wv.z, a2v);
                    a3v = fmaf(hv.w, wv.w, a3v);
                }
                #pragma unroll
                for (int q = 0; q < 16; ++q) {
                    float4 hv = h24[q], wv = WH[q];
                    a0  = fmaf(hv.x, wv.x, a0);
                    a1v = fmaf(hv.y, wv.y, a1v);
                    a2v = fmaf(hv.z, wv.z, a2v);
                    a3v = fmaf(hv.w, wv.w, a3v);
                }
                float pre = (a0 + a1v) + (a2v + a3v);
                act1[g] = is_tanh ? tanhfast(pre) : sigm(pre);
            }
        }
        __syncthreads();   // A: gate activations visible; state reads done
        if (tid < 64) {
            if (s < 2048) {
                float ii = act0[tid], ff = act0[64 + tid], gg = act0[128 + tid], oo = act0[192 + tid];
                cst = fmaf(ff, cst, ii * gg);
                h0[tid] = oo * tanhfast(cst);
            }
        } else if (tid >= 256 && tid < 320) {
            if (s >= 1) {
                int j = tid - 256;
                float ii = act1[j], ff = act1[64 + j], gg = act1[128 + j], oo = act1[192 + j];
                cst = fmaf(ff, cst, ii * gg);
                float h = oo * tanhfast(cst);
                h2[j] = h;
                h2out[((long)b * 2048 + (s - 1)) * 64 + j] = h;
            }
        }
        __syncthreads();   // B: new state visible
    }
}

// ---------------- FC head ----------------
__global__ __launch_bounds__(256) void fc_kernel(
    const float* __restrict__ h2o,
    const float* __restrict__ fc1w, const float* __restrict__ fc1b,
    const float* __restrict__ fc2w, const float* __restrict__ fc2b,
    float* __restrict__ out)
{
    int r = blockIdx.x * 256 + threadIdx.x;   // 32768 rows
    float h[64];
    const float4* hp = (const float4*)(h2o + (long)r * 64);
    #pragma unroll
    for (int i = 0; i < 16; ++i) {
        float4 v = hp[i];
        h[4 * i] = v.x; h[4 * i + 1] = v.y; h[4 * i + 2] = v.z; h[4 * i + 3] = v.w;
    }
    float l0 = fc2b[0], l1 = fc2b[1];
    #pragma unroll 4
    for (int j = 0; j < 32; ++j) {
        float z = fc1b[j];
        #pragma unroll
        for (int k = 0; k < 64; ++k) z = fmaf(h[k], fc1w[j * 64 + k], z);
        z = fmaxf(z, 0.0f);
        l0 = fmaf(z, fc2w[j], l0);
        l1 = fmaf(z, fc2w[32 + j], l1);
    }
    out[r * 2] = l0;
    out[r * 2 + 1] = l1;
}

extern "C" void kernel_launch(void* const* d_in, const int* in_sizes, int n_in,
                              void* d_out, int out_size, void* d_ws, size_t ws_size,
                              hipStream_t stream) {
    const float* x    = (const float*)d_in[0];
    const float* w1   = (const float*)d_in[1];
    const float* b1   = (const float*)d_in[2];
    const float* g1   = (const float*)d_in[3];
    const float* be1  = (const float*)d_in[4];
    const float* m1   = (const float*)d_in[5];
    const float* v1   = (const float*)d_in[6];
    const float* w2   = (const float*)d_in[7];
    const float* b2   = (const float*)d_in[8];
    const float* g2   = (const float*)d_in[9];
    const float* be2  = (const float*)d_in[10];
    const float* m2   = (const float*)d_in[11];
    const float* v2   = (const float*)d_in[12];
    const float* w3   = (const float*)d_in[13];
    const float* b3   = (const float*)d_in[14];
    const float* g3   = (const float*)d_in[15];
    const float* be3  = (const float*)d_in[16];
    const float* m3   = (const float*)d_in[17];
    const float* v3   = (const float*)d_in[18];
    const float* wih0 = (const float*)d_in[19];
    const float* whh0 = (const float*)d_in[20];
    const float* bih0 = (const float*)d_in[21];
    const float* bhh0 = (const float*)d_in[22];
    const float* wih1 = (const float*)d_in[23];
    const float* whh1 = (const float*)d_in[24];
    const float* bih1 = (const float*)d_in[25];
    const float* bhh1 = (const float*)d_in[26];
    const float* fc1w = (const float*)d_in[27];
    const float* fc1b = (const float*)d_in[28];
    const float* fc2w = (const float*)d_in[29];
    const float* fc2b = (const float*)d_in[30];
    float* out = (float*)d_out;

    float* ws    = (float*)d_ws;
    float* feats = ws;                            // 32768*16 floats (2 MB)
    float* h2o   = ws + 32768 * 16;               // 32768*64 floats (8 MB)
    float* w2t2  = ws + 32768 * 16 + 32768 * 64;  // 16384 floats

    hipLaunchKernelGGL(pack_w2_kernel, dim3(64), dim3(256), 0, stream, w2, w2t2);
    hipLaunchKernelGGL(cnn_kernel, dim3(32768), dim3(256), 0, stream,
                       x, w1, b1, g1, be1, m1, v1, b2, g2, be2, m2, v2,
                       w3, b3, g3, be3, m3, v3, w2t2, feats);
    hipLaunchKernelGGL(lstm_kernel, dim3(16), dim3(512), 0, stream,
                       feats, wih0, whh0, bih0, bhh0, wih1, whh1, bih1, bhh1, h2o);
    hipLaunchKernelGGL(fc_kernel, dim3(128), dim3(256), 0, stream,
                       h2o, fc1w, fc1b, fc2w, fc2b, out);
}

// Round 3
// 3161.348 us; speedup vs baseline: 1.0893x; 1.0893x over previous
//
#include <hip/hip_runtime.h>

#define EPSV 1e-5f

__device__ __forceinline__ float fast_rcp(float x) { return __builtin_amdgcn_rcpf(x); }
__device__ __forceinline__ float sigm(float x) { return fast_rcp(1.0f + __expf(-x)); }
__device__ __forceinline__ float tanhfast(float x) {
    float e = __expf(2.0f * x);
    return 1.0f - 2.0f * fast_rcp(e + 1.0f);
}
__device__ __forceinline__ void fma4(const float4 w, const float4 v,
                                     float& a0, float& a1, float& a2, float& a3) {
    a0 = fmaf(w.x, v.x, a0);
    a1 = fmaf(w.y, v.y, a1);
    a2 = fmaf(w.z, v.z, a2);
    a3 = fmaf(w.w, v.w, a3);
}

// ---------------- pack w2 (32,64,7) -> w2t2[(i*32+o)*8 + k] (k<7, pad 0) ----------------
__global__ void pack_w2_kernel(const float* __restrict__ w2, float* __restrict__ w2t2) {
    int j = blockIdx.x * 256 + threadIdx.x;
    if (j < 16384) {
        int i = j >> 8;
        int o = (j >> 3) & 31;
        int k = j & 7;
        w2t2[j] = (k < 7) ? w2[o * 448 + i * 7 + k] : 0.0f;
    }
}

// ---------------- CNN: one block per window (b,t) ---------------- (unchanged from R2)
__global__ __launch_bounds__(256) void cnn_kernel(
    const float* __restrict__ x,
    const float* __restrict__ w1, const float* __restrict__ b1,
    const float* __restrict__ g1, const float* __restrict__ be1,
    const float* __restrict__ m1, const float* __restrict__ v1,
    const float* __restrict__ b2,
    const float* __restrict__ g2, const float* __restrict__ be2,
    const float* __restrict__ m2, const float* __restrict__ v2,
    const float* __restrict__ w3, const float* __restrict__ b3,
    const float* __restrict__ g3, const float* __restrict__ be3,
    const float* __restrict__ m3, const float* __restrict__ v3,
    const float* __restrict__ w2t2,
    float* __restrict__ feats)
{
    __shared__ float winh[64];
    __shared__ float w1t[9 * 64];
    __shared__ float4 w3s4[512];
    __shared__ float  w3s1[512];
    __shared__ __align__(16) float a1[64 * 60 + 16];
    __shared__ __align__(16) float a2[32 * 56 + 16];
    __shared__ float s1[64], t1[64], s2[32], t2[32], s3[16], t3[16];
    __shared__ float psum[16 * 16];

    const int tid = threadIdx.x;
    const int w = blockIdx.x;
    const int b = w >> 11;
    const int t = w & 2047;

    for (int idx = tid; idx < 576; idx += 256) {
        int o = idx / 9, k = idx % 9;
        w1t[k * 64 + o] = w1[idx];
    }
    for (int idx = tid; idx < 512; idx += 256) {
        int i = idx >> 4, o = idx & 15;
        int base = o * 160 + i * 5;
        w3s4[idx] = make_float4(w3[base], w3[base + 1], w3[base + 2], w3[base + 3]);
        w3s1[idx] = w3[base + 4];
    }
    if (tid < 64) {
        float s = g1[tid] * rsqrtf(v1[tid] + EPSV);
        s1[tid] = s;
        t1[tid] = (b1[tid] - m1[tid]) * s + be1[tid];
    } else if (tid < 96) {
        int o = tid - 64;
        float s = g2[o] * rsqrtf(v2[o] + EPSV);
        s2[o] = s;
        t2[o] = (b2[o] - m2[o]) * s + be2[o];
    } else if (tid < 112) {
        int o = tid - 96;
        float s = g3[o] * rsqrtf(v3[o] + EPSV);
        s3[o] = s;
        t3[o] = (b3[o] - m3[o]) * s + be3[o];
    }
    if (tid < 64) {
        winh[tid] = 0.0f;
        float* r = &a1[tid * 60];
        r[0] = 0.f; r[1] = 0.f; r[2] = 0.f;
        r[53] = 0.f; r[54] = 0.f; r[55] = 0.f; r[56] = 0.f; r[57] = 0.f; r[58] = 0.f; r[59] = 0.f;
    }
    if (tid < 32) {
        float* r = &a2[tid * 56];
        r[0] = 0.f; r[1] = 0.f;
        r[52] = 0.f; r[53] = 0.f; r[54] = 0.f; r[55] = 0.f;
    }
    __syncthreads();
    if (tid < 50) {
        int gi = t + tid - 49;
        winh[4 + tid] = (gi >= 0) ? x[b * 2048 + gi] : 0.0f;
    }
    __syncthreads();

    {   // conv1
        int o = tid >> 2, pg = tid & 3;
        int p0 = pg * 13;
        float wv[9];
        #pragma unroll
        for (int k = 0; k < 9; ++k) wv[k] = w1t[k * 64 + o];
        float sc = s1[o], tc = t1[o];
        #pragma unroll
        for (int q = 0; q < 13; ++q) {
            int p = p0 + q;
            if (p < 50) {
                float acc = 0.0f;
                #pragma unroll
                for (int k = 0; k < 9; ++k) acc = fmaf(wv[k], winh[p + k], acc);
                a1[o * 60 + 3 + p] = fmaxf(acc * sc + tc, 0.0f);
            }
        }
    }
    __syncthreads();

    {   // conv2
        int o = tid >> 3, pg = tid & 7;
        float acc[8];
        #pragma unroll
        for (int q = 0; q < 8; ++q) acc[q] = 0.0f;
        for (int i = 0; i < 64; ++i) {
            const float4* ap = (const float4*)&a1[i * 60 + 8 * pg];
            float4 A0 = ap[0], A1 = ap[1], A2 = ap[2];
            float2 A3 = *(const float2*)&a1[i * 60 + 8 * pg + 12];
            const float4* wp = (const float4*)&w2t2[(i * 32 + o) * 8];
            float4 Wa = wp[0], Wb = wp[1];
            float av[14] = {A0.x, A0.y, A0.z, A0.w, A1.x, A1.y, A1.z, A1.w,
                            A2.x, A2.y, A2.z, A2.w, A3.x, A3.y};
            float wk[7] = {Wa.x, Wa.y, Wa.z, Wa.w, Wb.x, Wb.y, Wb.z};
            #pragma unroll
            for (int k = 0; k < 7; ++k) {
                #pragma unroll
                for (int q = 0; q < 8; ++q) acc[q] = fmaf(wk[k], av[q + k], acc[q]);
            }
        }
        float sc = s2[o], tc = t2[o];
        #pragma unroll
        for (int q = 0; q < 8; ++q) {
            int p = 8 * pg + q;
            if (p < 50) a2[o * 56 + 2 + p] = fmaxf(acc[q] * sc + tc, 0.0f);
        }
    }
    __syncthreads();

    {   // conv3 + mean partials
        int o = tid & 15, pg = tid >> 4;
        float acc[4];
        #pragma unroll
        for (int q = 0; q < 4; ++q) acc[q] = 0.0f;
        for (int i = 0; i < 32; ++i) {
            float4 wa = w3s4[i * 16 + o];
            float w4 = w3s1[i * 16 + o];
            const float4* ap = (const float4*)&a2[i * 56 + 4 * pg];
            float4 Aa = ap[0], Ab = ap[1];
            float av[8] = {Aa.x, Aa.y, Aa.z, Aa.w, Ab.x, Ab.y, Ab.z, Ab.w};
            #pragma unroll
            for (int q = 0; q < 4; ++q) {
                acc[q] = fmaf(wa.x, av[q], acc[q]);
                acc[q] = fmaf(wa.y, av[q + 1], acc[q]);
                acc[q] = fmaf(wa.z, av[q + 2], acc[q]);
                acc[q] = fmaf(wa.w, av[q + 3], acc[q]);
                acc[q] = fmaf(w4,   av[q + 4], acc[q]);
            }
        }
        float sc = s3[o], tc = t3[o];
        float ps = 0.0f;
        #pragma unroll
        for (int q = 0; q < 4; ++q) {
            int p = 4 * pg + q;
            if (p < 50) ps += fmaxf(acc[q] * sc + tc, 0.0f);
        }
        psum[pg * 16 + o] = ps;
    }
    __syncthreads();

    if (tid < 16) {
        float s = 0.0f;
        #pragma unroll
        for (int pg = 0; pg < 16; ++pg) s += psum[pg * 16 + tid];
        feats[w * 16 + tid] = s * (1.0f / 50.0f);
    }
}

// ---------------- LSTM: 16 persistent blocks, 1024 threads, 2 lanes per gate ----------------
// Waves 0-7: layer0 (512 lanes = 256 gates x 2 K-halves); waves 8-15: layer1 (one step behind).
// All weights in NAMED float4 SSA values (<=16 per thread) -> VGPR-resident by construction.
// Partial dots combined via __shfl_xor(.,1); h vectors read as broadcast ds_read_b128.
__global__ __launch_bounds__(1024, 4) void lstm_kernel(
    const float* __restrict__ feats,
    const float* __restrict__ wih0, const float* __restrict__ whh0,
    const float* __restrict__ bih0, const float* __restrict__ bhh0,
    const float* __restrict__ wih1, const float* __restrict__ whh1,
    const float* __restrict__ bih1, const float* __restrict__ bhh1,
    float* __restrict__ h2out)
{
    __shared__ __align__(16) float h1s[64];   // layer0 hidden (= layer1 input)
    __shared__ __align__(16) float h2s[64];   // layer1 hidden
    __shared__ float act0[256];
    __shared__ float act1[256];

    const int tid = threadIdx.x;
    const int b = blockIdx.x;
    const int layer = tid >> 9;       // wave-uniform
    const int id = tid & 511;
    const int g = id >> 1;            // gate 0..255
    const int hf = id & 1;            // K-half
    const bool is_tanh = ((g >> 6) == 2);

    const float* fbase = feats + (long)b * 2048 * 16;
    const float4 z4 = make_float4(0.f, 0.f, 0.f, 0.f);

    // X0..X7: layer1 = wih1 row-half; layer0 = {X0,X1 x-weights, X4,X5 current f, X6,X7 f-prefetch}
    // H0..H7: recurrent weights row-half for both layers
    float4 X0, X1, X2, X3, X4, X5, X6, X7, H0, H1, H2, H3, H4, H5, H6, H7;
    float bb;
    if (layer == 0) {
        const float4* whp = (const float4*)(whh0 + g * 64) + hf * 8;
        H0 = whp[0]; H1 = whp[1]; H2 = whp[2]; H3 = whp[3];
        H4 = whp[4]; H5 = whp[5]; H6 = whp[6]; H7 = whp[7];
        const float4* wxp = (const float4*)(wih0 + g * 16) + hf * 2;
        X0 = wxp[0]; X1 = wxp[1];
        X2 = z4; X3 = z4;
        const float4* fp = (const float4*)(fbase) + hf * 2;
        X4 = fp[0]; X5 = fp[1];           // f for step 0
        X6 = z4; X7 = z4;
        bb = bih0[g] + bhh0[g];
    } else {
        const float4* wxp = (const float4*)(wih1 + g * 64) + hf * 8;
        X0 = wxp[0]; X1 = wxp[1]; X2 = wxp[2]; X3 = wxp[3];
        X4 = wxp[4]; X5 = wxp[5]; X6 = wxp[6]; X7 = wxp[7];
        const float4* whp = (const float4*)(whh1 + g * 64) + hf * 8;
        H0 = whp[0]; H1 = whp[1]; H2 = whp[2]; H3 = whp[3];
        H4 = whp[4]; H5 = whp[5]; H6 = whp[6]; H7 = whp[7];
        bb = bih1[g] + bhh1[g];
    }

    if (tid < 64) h1s[tid] = 0.0f;
    else if (tid < 128) h2s[tid - 64] = 0.0f;
    float cst = 0.0f;
    __syncthreads();

    const float4* h1p = ((const float4*)h1s) + hf * 8;
    const float4* h2p = ((const float4*)h2s) + hf * 8;

    for (int s = 0; s <= 2048; ++s) {
        if (layer == 0) {
            if (s < 2048) {
                // issue next-step f prefetch first (consumed at the very end)
                int sn = (s + 1 < 2048) ? (s + 1) : 2047;
                const float4* fp = (const float4*)(fbase + sn * 16) + hf * 2;
                X6 = fp[0]; X7 = fp[1];
                float a0 = 0.f, a1 = 0.f, a2 = 0.f, a3 = 0.f;
                fma4(X0, X4, a0, a1, a2, a3);
                fma4(X1, X5, a0, a1, a2, a3);
                fma4(H0, h1p[0], a0, a1, a2, a3);
                fma4(H1, h1p[1], a0, a1, a2, a3);
                fma4(H2, h1p[2], a0, a1, a2, a3);
                fma4(H3, h1p[3], a0, a1, a2, a3);
                fma4(H4, h1p[4], a0, a1, a2, a3);
                fma4(H5, h1p[5], a0, a1, a2, a3);
                fma4(H6, h1p[6], a0, a1, a2, a3);
                fma4(H7, h1p[7], a0, a1, a2, a3);
                float part = (a0 + a1) + (a2 + a3);
                float tot = part + __shfl_xor(part, 1, 64) + bb;
                float av = is_tanh ? tanhfast(tot) : sigm(tot);
                if (hf == 0) act0[g] = av;
                X4 = X6; X5 = X7;     // rotate prefetch (vmcnt wait lands here, fully covered)
            }
        } else {
            if (s >= 1) {
                float a0 = 0.f, a1 = 0.f, a2 = 0.f, a3 = 0.f;
                fma4(X0, h1p[0], a0, a1, a2, a3);
                fma4(X1, h1p[1], a0, a1, a2, a3);
                fma4(X2, h1p[2], a0, a1, a2, a3);
                fma4(X3, h1p[3], a0, a1, a2, a3);
                fma4(X4, h1p[4], a0, a1, a2, a3);
                fma4(X5, h1p[5], a0, a1, a2, a3);
                fma4(X6, h1p[6], a0, a1, a2, a3);
                fma4(X7, h1p[7], a0, a1, a2, a3);
                fma4(H0, h2p[0], a0, a1, a2, a3);
                fma4(H1, h2p[1], a0, a1, a2, a3);
                fma4(H2, h2p[2], a0, a1, a2, a3);
                fma4(H3, h2p[3], a0, a1, a2, a3);
                fma4(H4, h2p[4], a0, a1, a2, a3);
                fma4(H5, h2p[5], a0, a1, a2, a3);
                fma4(H6, h2p[6], a0, a1, a2, a3);
                fma4(H7, h2p[7], a0, a1, a2, a3);
                float part = (a0 + a1) + (a2 + a3);
                float tot = part + __shfl_xor(part, 1, 64) + bb;
                float av = is_tanh ? tanhfast(tot) : sigm(tot);
                if (hf == 0) act1[g] = av;
            }
        }
        __syncthreads();   // A: activations visible; all state reads done
        if (tid >= 64 && tid < 128) {          // wave 1: layer0 state update
            if (s < 2048) {
                int j = tid - 64;
                float ii = act0[j], ff = act0[64 + j], gg = act0[128 + j], oo = act0[192 + j];
                cst = fmaf(ff, cst, ii * gg);
                h1s[j] = oo * tanhfast(cst);
            }
        } else if (tid >= 640 && tid < 704) {  // wave 10: layer1 state update
            if (s >= 1) {
                int j = tid - 640;
                float ii = act1[j], ff = act1[64 + j], gg = act1[128 + j], oo = act1[192 + j];
                cst = fmaf(ff, cst, ii * gg);
                float h = oo * tanhfast(cst);
                h2s[j] = h;
                h2out[((long)b * 2048 + (s - 1)) * 64 + j] = h;
            }
        }
        __syncthreads();   // B: new state visible
    }
}

// ---------------- FC head ----------------
__global__ __launch_bounds__(256) void fc_kernel(
    const float* __restrict__ h2o,
    const float* __restrict__ fc1w, const float* __restrict__ fc1b,
    const float* __restrict__ fc2w, const float* __restrict__ fc2b,
    float* __restrict__ out)
{
    int r = blockIdx.x * 256 + threadIdx.x;
    float h[64];
    const float4* hp = (const float4*)(h2o + (long)r * 64);
    #pragma unroll
    for (int i = 0; i < 16; ++i) {
        float4 v = hp[i];
        h[4 * i] = v.x; h[4 * i + 1] = v.y; h[4 * i + 2] = v.z; h[4 * i + 3] = v.w;
    }
    float l0 = fc2b[0], l1 = fc2b[1];
    #pragma unroll 4
    for (int j = 0; j < 32; ++j) {
        float z = fc1b[j];
        #pragma unroll
        for (int k = 0; k < 64; ++k) z = fmaf(h[k], fc1w[j * 64 + k], z);
        z = fmaxf(z, 0.0f);
        l0 = fmaf(z, fc2w[j], l0);
        l1 = fmaf(z, fc2w[32 + j], l1);
    }
    out[r * 2] = l0;
    out[r * 2 + 1] = l1;
}

extern "C" void kernel_launch(void* const* d_in, const int* in_sizes, int n_in,
                              void* d_out, int out_size, void* d_ws, size_t ws_size,
                              hipStream_t stream) {
    const float* x    = (const float*)d_in[0];
    const float* w1   = (const float*)d_in[1];
    const float* b1   = (const float*)d_in[2];
    const float* g1   = (const float*)d_in[3];
    const float* be1  = (const float*)d_in[4];
    const float* m1   = (const float*)d_in[5];
    const float* v1   = (const float*)d_in[6];
    const float* w2   = (const float*)d_in[7];
    const float* b2   = (const float*)d_in[8];
    const float* g2   = (const float*)d_in[9];
    const float* be2  = (const float*)d_in[10];
    const float* m2   = (const float*)d_in[11];
    const float* v2   = (const float*)d_in[12];
    const float* w3   = (const float*)d_in[13];
    const float* b3   = (const float*)d_in[14];
    const float* g3   = (const float*)d_in[15];
    const float* be3  = (const float*)d_in[16];
    const float* m3   = (const float*)d_in[17];
    const float* v3   = (const float*)d_in[18];
    const float* wih0 = (const float*)d_in[19];
    const float* whh0 = (const float*)d_in[20];
    const float* bih0 = (const float*)d_in[21];
    const float* bhh0 = (const float*)d_in[22];
    const float* wih1 = (const float*)d_in[23];
    const float* whh1 = (const float*)d_in[24];
    const float* bih1 = (const float*)d_in[25];
    const float* bhh1 = (const float*)d_in[26];
    const float* fc1w = (const float*)d_in[27];
    const float* fc1b = (const float*)d_in[28];
    const float* fc2w = (const float*)d_in[29];
    const float* fc2b = (const float*)d_in[30];
    float* out = (float*)d_out;

    float* ws    = (float*)d_ws;
    float* feats = ws;                            // 32768*16 floats (2 MB)
    float* h2o   = ws + 32768 * 16;               // 32768*64 floats (8 MB)
    float* w2t2  = ws + 32768 * 16 + 32768 * 64;  // 16384 floats

    hipLaunchKernelGGL(pack_w2_kernel, dim3(64), dim3(256), 0, stream, w2, w2t2);
    hipLaunchKernelGGL(cnn_kernel, dim3(32768), dim3(256), 0, stream,
                       x, w1, b1, g1, be1, m1, v1, b2, g2, be2, m2, v2,
                       w3, b3, g3, be3, m3, v3, w2t2, feats);
    hipLaunchKernelGGL(lstm_kernel, dim3(16), dim3(1024), 0, stream,
                       feats, wih0, whh0, bih0, bhh0, wih1, whh1, bih1, bhh1, h2o);
    hipLaunchKernelGGL(fc_kernel, dim3(128), dim3(256), 0, stream,
                       h2o, fc1w, fc1b, fc2w, fc2b, out);
}

// Round 4
// 2855.422 us; speedup vs baseline: 1.2060x; 1.1071x over previous
//
#include <hip/hip_runtime.h>

#define EPSV 1e-5f

__device__ __forceinline__ float fast_rcp(float x) { return __builtin_amdgcn_rcpf(x); }
__device__ __forceinline__ float sigm(float x) { return fast_rcp(1.0f + __expf(-x)); }
__device__ __forceinline__ float tanhfast(float x) {
    float e = __expf(2.0f * x);
    return 1.0f - 2.0f * fast_rcp(e + 1.0f);
}
__device__ __forceinline__ float dot4(const float4 w, const float4 v, float a) {
    a = fmaf(w.x, v.x, a);
    a = fmaf(w.y, v.y, a);
    a = fmaf(w.z, v.z, a);
    a = fmaf(w.w, v.w, a);
    return a;
}

// ---------------- pack: w2 -> w2t2[(i*32+o)*8+k]; w3 -> w3p4/w3p1[(i*16+o)] ----------------
__global__ void pack_kernel(const float* __restrict__ w2, const float* __restrict__ w3,
                            float* __restrict__ w2t2, float4* __restrict__ w3p4,
                            float* __restrict__ w3p1) {
    int j = blockIdx.x * 256 + threadIdx.x;
    if (j < 16384) {
        int i = j >> 8;
        int o = (j >> 3) & 31;
        int k = j & 7;
        w2t2[j] = (k < 7) ? w2[o * 448 + i * 7 + k] : 0.0f;
    } else if (j < 16896) {
        int e = j - 16384;            // e = i*16+o
        int i = e >> 4, o = e & 15;
        int base = o * 160 + i * 5;
        w3p4[e] = make_float4(w3[base], w3[base + 1], w3[base + 2], w3[base + 3]);
        w3p1[e] = w3[base + 4];
    }
}

// ---------------- CNN: one block per window (b,t) ----------------
// a1 layout: slot sigma(pi) = pi + 4*(pi>>3) for pi = p+3 in [0,55]; row stride 84.
//   -> conv2 pg reads start at 12*pg: bank-groups {0,12,24,4,16,28,8,20} = all 32 banks,
//      ZERO b128 bank conflicts (the 8-float-stride layout had 2-way aliasing on every read).
// a2: stride 56, slot = p+2; stores vectorized f2/f4/f2 (was 8 scalars with 16-way conflicts).
__global__ __launch_bounds__(256) void cnn_kernel(
    const float* __restrict__ x,
    const float* __restrict__ w1, const float* __restrict__ b1,
    const float* __restrict__ g1, const float* __restrict__ be1,
    const float* __restrict__ m1, const float* __restrict__ v1,
    const float* __restrict__ b2,
    const float* __restrict__ g2, const float* __restrict__ be2,
    const float* __restrict__ m2, const float* __restrict__ v2,
    const float* __restrict__ b3,
    const float* __restrict__ g3, const float* __restrict__ be3,
    const float* __restrict__ m3, const float* __restrict__ v3,
    const float* __restrict__ w2t2,
    const float4* __restrict__ w3p4, const float* __restrict__ w3p1,
    float* __restrict__ feats)
{
    __shared__ float winh[64];
    __shared__ float w1t[9 * 64];
    __shared__ __align__(16) float a1[64 * 84 + 32];
    __shared__ __align__(16) float a2[32 * 56 + 16];
    __shared__ float s1[64], t1[64], s2[32], t2[32], s3[16], t3[16];
    __shared__ float psum[16 * 16];

    const int tid = threadIdx.x;
    const int w = blockIdx.x;
    const int b = w >> 11;
    const int t = w & 2047;

    for (int idx = tid; idx < 576; idx += 256) {
        int o = idx / 9, k = idx % 9;
        w1t[k * 64 + o] = w1[idx];
    }
    if (tid < 64) {
        float s = g1[tid] * rsqrtf(v1[tid] + EPSV);
        s1[tid] = s;
        t1[tid] = (b1[tid] - m1[tid]) * s + be1[tid];
    } else if (tid < 96) {
        int o = tid - 64;
        float s = g2[o] * rsqrtf(v2[o] + EPSV);
        s2[o] = s;
        t2[o] = (b2[o] - m2[o]) * s + be2[o];
    } else if (tid < 112) {
        int o = tid - 96;
        float s = g3[o] * rsqrtf(v3[o] + EPSV);
        s3[o] = s;
        t3[o] = (b3[o] - m3[o]) * s + be3[o];
    }
    if (tid < 64) {
        winh[tid] = 0.0f;
        float* r = &a1[tid * 84];
        // zero halo slots: pi=0,1,2 -> sigma 0,1,2 ; pi=53,54,55 -> sigma 77,78,79
        r[0] = 0.f; r[1] = 0.f; r[2] = 0.f;
        r[77] = 0.f; r[78] = 0.f; r[79] = 0.f;
    }
    if (tid < 32) {
        float* r = &a2[tid * 56];
        r[0] = 0.f; r[1] = 0.f;
        r[52] = 0.f; r[53] = 0.f; r[54] = 0.f; r[55] = 0.f;
    }
    __syncthreads();
    if (tid < 50) {
        int gi = t + tid - 49;
        winh[4 + tid] = (gi >= 0) ? x[b * 2048 + gi] : 0.0f;
    }
    __syncthreads();

    {   // conv1: 64 o x 4 pgroups of 13
        int o = tid >> 2, pg = tid & 3;
        int p0 = pg * 13;
        float wv[9];
        #pragma unroll
        for (int k = 0; k < 9; ++k) wv[k] = w1t[k * 64 + o];
        float sc = s1[o], tc = t1[o];
        #pragma unroll
        for (int q = 0; q < 13; ++q) {
            int p = p0 + q;
            if (p < 50) {
                float acc = 0.0f;
                #pragma unroll
                for (int k = 0; k < 9; ++k) acc = fmaf(wv[k], winh[p + k], acc);
                int pi = p + 3;
                int slot = pi + ((pi >> 3) << 2);
                a1[o * 84 + slot] = fmaxf(acc * sc + tc, 0.0f);
            }
        }
    }
    __syncthreads();

    {   // conv2: 32 o x 8 pgroups of 8 positions
        int o = tid >> 3, pg = tid & 7;
        float acc[8];
        #pragma unroll
        for (int q = 0; q < 8; ++q) acc[q] = 0.0f;
        for (int i = 0; i < 64; ++i) {
            const float* rowp = &a1[i * 84 + 12 * pg];
            float4 A0 = *(const float4*)&rowp[0];
            float4 A1 = *(const float4*)&rowp[4];
            float4 A2 = *(const float4*)&rowp[12];
            float2 A3 = *(const float2*)&rowp[16];
            const float4* wp = (const float4*)&w2t2[(i * 32 + o) * 8];
            float4 Wa = wp[0], Wb = wp[1];
            float av[14] = {A0.x, A0.y, A0.z, A0.w, A1.x, A1.y, A1.z, A1.w,
                            A2.x, A2.y, A2.z, A2.w, A3.x, A3.y};
            float wk[7] = {Wa.x, Wa.y, Wa.z, Wa.w, Wb.x, Wb.y, Wb.z};
            #pragma unroll
            for (int k = 0; k < 7; ++k) {
                #pragma unroll
                for (int q = 0; q < 8; ++q) acc[q] = fmaf(wk[k], av[q + k], acc[q]);
            }
        }
        float sc = s2[o], tc = t2[o];
        float r[8];
        #pragma unroll
        for (int q = 0; q < 8; ++q) r[q] = fmaxf(acc[q] * sc + tc, 0.0f);
        float* row = &a2[o * 56 + 8 * pg];   // slot = 8pg+2+q
        if (pg < 6) {
            *(float2*)&row[2] = make_float2(r[0], r[1]);
            *(float4*)&row[4] = make_float4(r[2], r[3], r[4], r[5]);
            *(float2*)&row[8] = make_float2(r[6], r[7]);
        } else if (pg == 6) {
            *(float2*)&row[2] = make_float2(r[0], r[1]);  // p = 48,49 only
        }
    }
    __syncthreads();

    {   // conv3 + bn3 + relu + partial mean: 16 o x 16 pgroups of 4
        int o = tid & 15, pg = tid >> 4;
        float acc[4];
        #pragma unroll
        for (int q = 0; q < 4; ++q) acc[q] = 0.0f;
        for (int i = 0; i < 32; ++i) {
            float4 wa = w3p4[i * 16 + o];
            float w4 = w3p1[i * 16 + o];
            const float4* ap = (const float4*)&a2[i * 56 + 4 * pg];
            float4 Aa = ap[0], Ab = ap[1];
            float av[8] = {Aa.x, Aa.y, Aa.z, Aa.w, Ab.x, Ab.y, Ab.z, Ab.w};
            #pragma unroll
            for (int q = 0; q < 4; ++q) {
                acc[q] = fmaf(wa.x, av[q], acc[q]);
                acc[q] = fmaf(wa.y, av[q + 1], acc[q]);
                acc[q] = fmaf(wa.z, av[q + 2], acc[q]);
                acc[q] = fmaf(wa.w, av[q + 3], acc[q]);
                acc[q] = fmaf(w4,   av[q + 4], acc[q]);
            }
        }
        float sc = s3[o], tc = t3[o];
        float ps = 0.0f;
        #pragma unroll
        for (int q = 0; q < 4; ++q) {
            int p = 4 * pg + q;
            if (p < 50) ps += fmaxf(acc[q] * sc + tc, 0.0f);
        }
        psum[pg * 16 + o] = ps;
    }
    __syncthreads();

    if (tid < 16) {
        float s = 0.0f;
        #pragma unroll
        for (int pg = 0; pg < 16; ++pg) s += psum[pg * 16 + tid];
        feats[w * 16 + tid] = s * (1.0f / 50.0f);
    }
}

// ---------------- LSTM: 16 persistent blocks, 1024 threads ----------------
// 8 lanes per h-element j compute ALL 4 gates (K split 8-way), butterfly-reduced via
// __shfl_xor; c kept redundantly in-register across the 8 lanes (bitwise-identical math);
// h double-buffered by step parity -> ONE barrier per step, zero act-LDS round trips.
// Waves 0-7: layer0; waves 8-15: layer1 one step behind.
__global__ __launch_bounds__(1024, 4) void lstm_kernel(
    const float* __restrict__ feats,
    const float* __restrict__ wih0, const float* __restrict__ whh0,
    const float* __restrict__ bih0, const float* __restrict__ bhh0,
    const float* __restrict__ wih1, const float* __restrict__ whh1,
    const float* __restrict__ bih1, const float* __restrict__ bhh1,
    float* __restrict__ h2out)
{
    __shared__ __align__(16) float h1b[2][64];
    __shared__ __align__(16) float h2b[2][64];

    const int tid = threadIdx.x;
    const int b = blockIdx.x;
    const int layer = tid >> 9;   // wave-uniform
    const int id = tid & 511;
    const int j = id >> 3;        // h-element 0..63
    const int l = id & 7;         // K-slice 0..7

    const float* fbase = feats + (long)b * 2048 * 16;
    const float4 z4 = make_float4(0.f, 0.f, 0.f, 0.f);

    float4 WH0a = z4, WH0b = z4, WH1a = z4, WH1b = z4,
           WH2a = z4, WH2b = z4, WH3a = z4, WH3b = z4;
    float4 WX0a = z4, WX0b = z4, WX1a = z4, WX1b = z4,
           WX2a = z4, WX2b = z4, WX3a = z4, WX3b = z4;
    float2 xw0 = make_float2(0.f, 0.f), xw1 = xw0, xw2 = xw0, xw3 = xw0;
    float bb0, bb1, bb2, bb3;

    if (layer == 0) {
        const float4* p0 = (const float4*)(whh0 + (0 * 64 + j) * 64 + l * 8);
        const float4* p1 = (const float4*)(whh0 + (1 * 64 + j) * 64 + l * 8);
        const float4* p2 = (const float4*)(whh0 + (2 * 64 + j) * 64 + l * 8);
        const float4* p3 = (const float4*)(whh0 + (3 * 64 + j) * 64 + l * 8);
        WH0a = p0[0]; WH0b = p0[1]; WH1a = p1[0]; WH1b = p1[1];
        WH2a = p2[0]; WH2b = p2[1]; WH3a = p3[0]; WH3b = p3[1];
        xw0 = *(const float2*)(wih0 + (0 * 64 + j) * 16 + l * 2);
        xw1 = *(const float2*)(wih0 + (1 * 64 + j) * 16 + l * 2);
        xw2 = *(const float2*)(wih0 + (2 * 64 + j) * 16 + l * 2);
        xw3 = *(const float2*)(wih0 + (3 * 64 + j) * 16 + l * 2);
        bb0 = bih0[j] + bhh0[j];
        bb1 = bih0[64 + j] + bhh0[64 + j];
        bb2 = bih0[128 + j] + bhh0[128 + j];
        bb3 = bih0[192 + j] + bhh0[192 + j];
    } else {
        const float4* q0 = (const float4*)(wih1 + (0 * 64 + j) * 64 + l * 8);
        const float4* q1 = (const float4*)(wih1 + (1 * 64 + j) * 64 + l * 8);
        const float4* q2 = (const float4*)(wih1 + (2 * 64 + j) * 64 + l * 8);
        const float4* q3 = (const float4*)(wih1 + (3 * 64 + j) * 64 + l * 8);
        WX0a = q0[0]; WX0b = q0[1]; WX1a = q1[0]; WX1b = q1[1];
        WX2a = q2[0]; WX2b = q2[1]; WX3a = q3[0]; WX3b = q3[1];
        const float4* p0 = (const float4*)(whh1 + (0 * 64 + j) * 64 + l * 8);
        const float4* p1 = (const float4*)(whh1 + (1 * 64 + j) * 64 + l * 8);
        const float4* p2 = (const float4*)(whh1 + (2 * 64 + j) * 64 + l * 8);
        const float4* p3 = (const float4*)(whh1 + (3 * 64 + j) * 64 + l * 8);
        WH0a = p0[0]; WH0b = p0[1]; WH1a = p1[0]; WH1b = p1[1];
        WH2a = p2[0]; WH2b = p2[1]; WH3a = p3[0]; WH3b = p3[1];
        bb0 = bih1[j] + bhh1[j];
        bb1 = bih1[64 + j] + bhh1[64 + j];
        bb2 = bih1[128 + j] + bhh1[128 + j];
        bb3 = bih1[192 + j] + bhh1[192 + j];
    }

    float2 Fc = make_float2(0.f, 0.f);
    if (layer == 0) Fc = *(const float2*)(fbase + l * 2);
    float cst = 0.0f;

    if (tid < 128) ((float*)h1b)[tid] = 0.0f;
    else if (tid < 256) ((float*)h2b)[tid - 128] = 0.0f;
    __syncthreads();

    for (int s = 0; s <= 2048; ++s) {
        const int rp = (s + 1) & 1;   // buffer holding state of step s-1 (h1) / s-2 -> write tgt (h2)
        const int wp = s & 1;
        if (layer == 0) {
            if (s < 2048) {
                int sn = (s + 1 < 2048) ? (s + 1) : 2047;
                float2 Fn = *(const float2*)(fbase + sn * 16 + l * 2);  // prefetch next step
                const float4* hp = (const float4*)&h1b[rp][l * 8];
                float4 hv0 = hp[0], hv1 = hp[1];
                float a0 = dot4(WH0b, hv1, dot4(WH0a, hv0, fmaf(xw0.x, Fc.x, xw0.y * Fc.y)));
                float a1 = dot4(WH1b, hv1, dot4(WH1a, hv0, fmaf(xw1.x, Fc.x, xw1.y * Fc.y)));
                float a2 = dot4(WH2b, hv1, dot4(WH2a, hv0, fmaf(xw2.x, Fc.x, xw2.y * Fc.y)));
                float a3 = dot4(WH3b, hv1, dot4(WH3a, hv0, fmaf(xw3.x, Fc.x, xw3.y * Fc.y)));
                a0 += __shfl_xor(a0, 1); a0 += __shfl_xor(a0, 2); a0 += __shfl_xor(a0, 4);
                a1 += __shfl_xor(a1, 1); a1 += __shfl_xor(a1, 2); a1 += __shfl_xor(a1, 4);
                a2 += __shfl_xor(a2, 1); a2 += __shfl_xor(a2, 2); a2 += __shfl_xor(a2, 4);
                a3 += __shfl_xor(a3, 1); a3 += __shfl_xor(a3, 2); a3 += __shfl_xor(a3, 4);
                float gi = sigm(a0 + bb0), gf = sigm(a1 + bb1);
                float gg = tanhfast(a2 + bb2), go = sigm(a3 + bb3);
                cst = fmaf(gf, cst, gi * gg);
                float h = go * tanhfast(cst);
                if (l == 0) h1b[wp][j] = h;
                Fc = Fn;
            }
        } else {
            if (s >= 1) {
                const float4* xp = (const float4*)&h1b[rp][l * 8];   // h1(s-1)
                float4 xv0 = xp[0], xv1 = xp[1];
                const float4* hp = (const float4*)&h2b[wp][l * 8];   // h2(s-2)
                float4 hv0 = hp[0], hv1 = hp[1];
                float a0 = dot4(WH0b, hv1, dot4(WH0a, hv0, dot4(WX0b, xv1, dot4(WX0a, xv0, 0.f))));
                float a1 = dot4(WH1b, hv1, dot4(WH1a, hv0, dot4(WX1b, xv1, dot4(WX1a, xv0, 0.f))));
                float a2 = dot4(WH2b, hv1, dot4(WH2a, hv0, dot4(WX2b, xv1, dot4(WX2a, xv0, 0.f))));
                float a3 = dot4(WH3b, hv1, dot4(WH3a, hv0, dot4(WX3b, xv1, dot4(WX3a, xv0, 0.f))));
                a0 += __shfl_xor(a0, 1); a0 += __shfl_xor(a0, 2); a0 += __shfl_xor(a0, 4);
                a1 += __shfl_xor(a1, 1); a1 += __shfl_xor(a1, 2); a1 += __shfl_xor(a1, 4);
                a2 += __shfl_xor(a2, 1); a2 += __shfl_xor(a2, 2); a2 += __shfl_xor(a2, 4);
                a3 += __shfl_xor(a3, 1); a3 += __shfl_xor(a3, 2); a3 += __shfl_xor(a3, 4);
                float gi = sigm(a0 + bb0), gf = sigm(a1 + bb1);
                float gg = tanhfast(a2 + bb2), go = sigm(a3 + bb3);
                cst = fmaf(gf, cst, gi * gg);
                float h = go * tanhfast(cst);
                if (l == 0) {
                    h2b[rp][j] = h;                                   // h2(s-1) -> parity (s-1)&1
                    h2out[((long)b * 2048 + (s - 1)) * 64 + j] = h;
                }
            }
        }
        __syncthreads();   // writes of this iteration visible to next
    }
}

// ---------------- FC head ----------------
__global__ __launch_bounds__(256) void fc_kernel(
    const float* __restrict__ h2o,
    const float* __restrict__ fc1w, const float* __restrict__ fc1b,
    const float* __restrict__ fc2w, const float* __restrict__ fc2b,
    float* __restrict__ out)
{
    int r = blockIdx.x * 256 + threadIdx.x;
    float h[64];
    const float4* hp = (const float4*)(h2o + (long)r * 64);
    #pragma unroll
    for (int i = 0; i < 16; ++i) {
        float4 v = hp[i];
        h[4 * i] = v.x; h[4 * i + 1] = v.y; h[4 * i + 2] = v.z; h[4 * i + 3] = v.w;
    }
    float l0 = fc2b[0], l1 = fc2b[1];
    #pragma unroll 4
    for (int j = 0; j < 32; ++j) {
        float z = fc1b[j];
        #pragma unroll
        for (int k = 0; k < 64; ++k) z = fmaf(h[k], fc1w[j * 64 + k], z);
        z = fmaxf(z, 0.0f);
        l0 = fmaf(z, fc2w[j], l0);
        l1 = fmaf(z, fc2w[32 + j], l1);
    }
    out[r * 2] = l0;
    out[r * 2 + 1] = l1;
}

extern "C" void kernel_launch(void* const* d_in, const int* in_sizes, int n_in,
                              void* d_out, int out_size, void* d_ws, size_t ws_size,
                              hipStream_t stream) {
    const float* x    = (const float*)d_in[0];
    const float* w1   = (const float*)d_in[1];
    const float* b1   = (const float*)d_in[2];
    const float* g1   = (const float*)d_in[3];
    const float* be1  = (const float*)d_in[4];
    const float* m1   = (const float*)d_in[5];
    const float* v1   = (const float*)d_in[6];
    const float* w2   = (const float*)d_in[7];
    const float* b2   = (const float*)d_in[8];
    const float* g2   = (const float*)d_in[9];
    const float* be2  = (const float*)d_in[10];
    const float* m2   = (const float*)d_in[11];
    const float* v2   = (const float*)d_in[12];
    const float* w3   = (const float*)d_in[13];
    const float* b3   = (const float*)d_in[14];
    const float* g3   = (const float*)d_in[15];
    const float* be3  = (const float*)d_in[16];
    const float* m3   = (const float*)d_in[17];
    const float* v3   = (const float*)d_in[18];
    const float* wih0 = (const float*)d_in[19];
    const float* whh0 = (const float*)d_in[20];
    const float* bih0 = (const float*)d_in[21];
    const float* bhh0 = (const float*)d_in[22];
    const float* wih1 = (const float*)d_in[23];
    const float* whh1 = (const float*)d_in[24];
    const float* bih1 = (const float*)d_in[25];
    const float* bhh1 = (const float*)d_in[26];
    const float* fc1w = (const float*)d_in[27];
    const float* fc1b = (const float*)d_in[28];
    const float* fc2w = (const float*)d_in[29];
    const float* fc2b = (const float*)d_in[30];
    float* out = (float*)d_out;

    float* ws    = (float*)d_ws;
    float* feats = ws;                            // 524288 floats
    float* h2o   = ws + 32768 * 16;               // 2097152 floats
    float* w2t2  = ws + 32768 * 16 + 32768 * 64;  // 16384 floats
    float* w3p4f = w2t2 + 16384;                  // 2048 floats (512 float4, 16B-aligned)
    float* w3p1  = w3p4f + 2048;                  // 512 floats

    hipLaunchKernelGGL(pack_kernel, dim3(66), dim3(256), 0, stream,
                       w2, w3, w2t2, (float4*)w3p4f, w3p1);
    hipLaunchKernelGGL(cnn_kernel, dim3(32768), dim3(256), 0, stream,
                       x, w1, b1, g1, be1, m1, v1, b2, g2, be2, m2, v2,
                       b3, g3, be3, m3, v3, w2t2, (const float4*)w3p4f, w3p1, feats);
    hipLaunchKernelGGL(lstm_kernel, dim3(16), dim3(1024), 0, stream,
                       feats, wih0, whh0, bih0, bhh0, wih1, whh1, bih1, bhh1, h2o);
    hipLaunchKernelGGL(fc_kernel, dim3(128), dim3(256), 0, stream,
                       h2o, fc1w, fc1b, fc2w, fc2b, out);
}